// Round 6
// baseline (125.162 us; speedup 1.0000x reference)
//
#include <hip/hip_runtime.h>

#define Bn 16
#define Ln 128
#define Hn 256
#define Dn 256

// Output layout (flat fp32 concat, reference return order)
#define OFF_MASK   0          // (B,L,L) 262144
#define OFF_SMP    262144     // (B,L,L) 262144
#define OFF_ENT    524288     // (B,L,L) 262144
#define OFF_GRAPH  786432     // (L,L)   16384
#define OFF_LSE    802816     // scalar
#define OFF_EREG   802817     // (B,)    16

static __device__ __forceinline__ unsigned rotl32(unsigned x, int r) {
  return (x << r) | (x >> (32 - r));
}

// Threefry-2x32, 20 rounds, key = (0,1)  [jax.random.key(1)], partitionable
// random-bits path: counter = (hi=0, lo=flat_index), output = y0 ^ y1.
static __device__ __forceinline__ unsigned threefry_bits(unsigned c_hi, unsigned c_lo) {
  const unsigned ks0 = 0u, ks1 = 1u;
  const unsigned ks2 = 0u ^ 1u ^ 0x1BD11BDAu;
  unsigned x0 = c_hi + ks0;
  unsigned x1 = c_lo + ks1;
  x0 += x1; x1 = rotl32(x1, 13); x1 ^= x0;
  x0 += x1; x1 = rotl32(x1, 15); x1 ^= x0;
  x0 += x1; x1 = rotl32(x1, 26); x1 ^= x0;
  x0 += x1; x1 = rotl32(x1, 6);  x1 ^= x0;
  x0 += ks1; x1 += ks2 + 1u;
  x0 += x1; x1 = rotl32(x1, 17); x1 ^= x0;
  x0 += x1; x1 = rotl32(x1, 29); x1 ^= x0;
  x0 += x1; x1 = rotl32(x1, 16); x1 ^= x0;
  x0 += x1; x1 = rotl32(x1, 24); x1 ^= x0;
  x0 += ks2; x1 += ks0 + 2u;
  x0 += x1; x1 = rotl32(x1, 13); x1 ^= x0;
  x0 += x1; x1 = rotl32(x1, 15); x1 ^= x0;
  x0 += x1; x1 = rotl32(x1, 26); x1 ^= x0;
  x0 += x1; x1 = rotl32(x1, 6);  x1 ^= x0;
  x0 += ks0; x1 += ks1 + 3u;
  x0 += x1; x1 = rotl32(x1, 17); x1 ^= x0;
  x0 += x1; x1 = rotl32(x1, 29); x1 ^= x0;
  x0 += x1; x1 = rotl32(x1, 16); x1 ^= x0;
  x0 += x1; x1 = rotl32(x1, 24); x1 ^= x0;
  x0 += ks1; x1 += ks2 + 4u;
  x0 += x1; x1 = rotl32(x1, 13); x1 ^= x0;
  x0 += x1; x1 = rotl32(x1, 15); x1 ^= x0;
  x0 += x1; x1 = rotl32(x1, 26); x1 ^= x0;
  x0 += x1; x1 = rotl32(x1, 6);  x1 ^= x0;
  x0 += ks2; x1 += ks0 + 5u;
  return x0 ^ x1;
}

static __device__ __forceinline__ float softplus_f(float x) {
  // max(x,0) + log1p(exp(-|x|)); exact at |x|=1e8 (exp(-1e8)=0)
  return fmaxf(x, 0.0f) + log1pf(__expf(-fabsf(x)));
}

static __device__ __forceinline__ float fast_tanh(float x) {
  // tanh(x) = 2/(1+e^{-2x}) - 1; saturates correctly for |x| large
  float e = __expf(-2.0f * x);
  float r = __builtin_amdgcn_rcpf(1.0f + e);
  return fmaf(2.0f, r, -1.0f);
}

// proj v6: v5 structure (512 blocks = rg:256 x mat:2, 8 rows x 256 cols,
// thread = 2 rows x 4 cols, float4 W loads, scalar wave-uniform enc loads)
// with a deeper pipeline: unroll 4 lets 2-3 iterations' W loads stay in
// flight (~300cy L2 latency vs ~128cy fma-issue per iter was a ~60% stall
// at 2 waves/SIMD). launch_bounds(256,2) caps VGPR at 256: room for the
// rotated load buffers, no R2-style spill. Chain order unchanged ->
// dl/dr bit-identical.
__global__ __launch_bounds__(256, 2) void proj_kernel(
                            const float* __restrict__ enc,
                            const float* __restrict__ Wl,
                            const float* __restrict__ Wr,
                            float* __restrict__ dl,
                            float* __restrict__ dr,
                            float* __restrict__ out,
                            double* __restrict__ ws_acc) {
  int gid = blockIdx.x * blockDim.x + threadIdx.x;
  if (gid < Ln * Ln) out[OFF_GRAPH + gid] = 0.0f;
  if (gid < 18) ws_acc[gid] = 0.0;

  int g = blockIdx.x;            // 512 blocks
  int rg = g >> 1;               // 0..255 -> 8-row group
  int mat = g & 1;               // 0 -> Wl/dl, 1 -> Wr/dr
  int r0 = rg * 8;

  int t = threadIdx.x;
  int d4 = (t & 63) * 4;         // 4 consecutive d-cols; lanes -> 1KB coalesced
  int rsub = t >> 6;             // wave id -> row pair

  // wave-uniform row index -> SGPR -> scalar loads of enc
  int row0 = __builtin_amdgcn_readfirstlane(r0 + rsub * 2);
  const float* ep0 = enc + (size_t)row0 * Hn;
  const float* ep1 = ep0 + Hn;
  const float* wbase = (mat ? Wr : Wl) + d4;

  float4 a0 = {0.f, 0.f, 0.f, 0.f};
  float4 a1 = {0.f, 0.f, 0.f, 0.f};

#pragma unroll 4
  for (int h8 = 0; h8 < Hn / 8; ++h8) {
    float4 w[8];
#pragma unroll
    for (int u = 0; u < 8; ++u)
      w[u] = *(const float4*)(wbase + (size_t)(h8 * 8 + u) * Dn);
#pragma unroll
    for (int u = 0; u < 8; ++u) {
      int h = h8 * 8 + u;        // h ascending overall -> same chain order
      float e0 = ep0[h];
      float e1 = ep1[h];
      a0.x = fmaf(e0, w[u].x, a0.x);
      a0.y = fmaf(e0, w[u].y, a0.y);
      a0.z = fmaf(e0, w[u].z, a0.z);
      a0.w = fmaf(e0, w[u].w, a0.w);
      a1.x = fmaf(e1, w[u].x, a1.x);
      a1.y = fmaf(e1, w[u].y, a1.y);
      a1.z = fmaf(e1, w[u].z, a1.z);
      a1.w = fmaf(e1, w[u].w, a1.w);
    }
  }

  float* dst = (mat ? dr : dl) + (size_t)(r0 + rsub * 2) * Dn + d4;
  *(float4*)dst = a0;
  *(float4*)(dst + Dn) = a1;
}

// Grid 1024 = (b:16, iq:32, jseg:2); block = 4 i-rows x 64 j x 256 d.
// EXACT R3 compute/schedule (48us proven; R5's launch_bounds+prefetch
// regressed to 65 and is reverted). ONE addressing-only change: dlS is now
// [4][16][20] (80B rows, 16B-aligned). The dlr fragment reads at the old
// dp*64B stride were an 8-way bank conflict (917K cycles = nearly all of
// SQ_LDS_BANK_CONFLICT); dp*20 mod 32 spreads 16 dp-values over 2-way max
// (free). Values identical -> outputs bit-identical.
__global__ void pair_kernel(const float* __restrict__ dl,
                            const float* __restrict__ dr,
                            const float* __restrict__ U,
                            const float* __restrict__ bias,
                            float* __restrict__ out,
                            double* __restrict__ ws_acc) {
  int blk = blockIdx.x;          // b*64 + iq*2 + jseg
  int b = blk >> 6;              // 0..15
  int i0 = ((blk >> 1) & 31) * 4;
  int j0 = (blk & 1) * 64;
  int t = threadIdx.x;
  int dp = t & 15;
  int jj = t >> 4;

  __shared__ float dlS[4][16][20];    // 5 KB, padded anti-conflict layout
  __shared__ float pS[4][64 * 17];    // [row][jl*17 + dp], padded, 17 KB
  __shared__ float redS[8];

  // stage dl rows i0..i0+3: same coalesced float4 source, padded LDS dest
  {
    int srow = t >> 6, sc = t & 63;
    *(float4*)&dlS[srow][sc >> 2][(sc & 3) * 4] =
        ((const float4*)(dl + (size_t)(b * Ln + i0) * Dn))[t];
  }

  float Ur[16];
  {
    const float4* U4 = (const float4*)(U + dp * 16);
#pragma unroll
    for (int q = 0; q < 4; ++q) {
      float4 u = U4[q];
      Ur[4*q+0] = u.x; Ur[4*q+1] = u.y; Ur[4*q+2] = u.z; Ur[4*q+3] = u.w;
    }
  }
  __syncthreads();

  float dlr[4][16];
#pragma unroll
  for (int r = 0; r < 4; ++r) {
#pragma unroll
    for (int q = 0; q < 4; ++q) {
      float4 a = *(const float4*)&dlS[r][dp][q * 4];
      dlr[r][4*q+0] = a.x; dlr[r][4*q+1] = a.y; dlr[r][4*q+2] = a.z; dlr[r][4*q+3] = a.w;
    }
  }

  const float* drt = dr + (size_t)b * Ln * Dn + (size_t)(j0 + jj) * Dn + dp * 16;
#pragma unroll
  for (int tl = 0; tl < 4; ++tl) {
    const float4* drp = (const float4*)(drt + (size_t)tl * 16 * Dn);
    float a0 = 0.f, a1 = 0.f, a2 = 0.f, a3 = 0.f;
#pragma unroll
    for (int q = 0; q < 4; ++q) {
      float4 v = drp[q];
#pragma unroll
      for (int c = 0; c < 4; ++c) {
        float dv = (c == 0) ? v.x : (c == 1) ? v.y : (c == 2) ? v.z : v.w;
        float uv = Ur[4*q+c];
        a0 = fmaf(fast_tanh(dlr[0][4*q+c] + dv), uv, a0);
        a1 = fmaf(fast_tanh(dlr[1][4*q+c] + dv), uv, a1);
        a2 = fmaf(fast_tanh(dlr[2][4*q+c] + dv), uv, a2);
        a3 = fmaf(fast_tanh(dlr[3][4*q+c] + dv), uv, a3);
      }
    }
    int sa = (tl * 16 + jj) * 17 + dp;   // jl*17 + dp, jl = tl*16+jj
    pS[0][sa] = a0; pS[1][sa] = a1; pS[2][sa] = a2; pS[3][sa] = a3;
  }
  __syncthreads();

  // epilogue: 256 outputs (4 rows x 64 j); thread t -> row = t>>6, jl = t&63
  int row = t >> 6;
  int jl = t & 63;
  int j = j0 + jl;
  const float* ps = &pS[row][jl * 17];
  float tot = 0.0f;
#pragma unroll
  for (int k = 0; k < 16; ++k) tot += ps[k];   // dp-ascending, same as R9
  int i = i0 + row;
  float l = tot + bias[0] - ((j == i) ? 1.0e8f : 0.0f);
  float e = __expf(-l);                       // l=-1e8 -> inf
  float p = __builtin_amdgcn_rcpf(1.0f + e);  // -> 0 on diagonal
  unsigned n = ((unsigned)(b * Ln + i) << 7) | (unsigned)j;
  unsigned bits = threefry_bits(0u, n);
  float u = __uint_as_float((bits >> 9) | 0x3f800000u) - 1.0f;
  float smp = (u < p) ? 1.0f : 0.0f;
  float sp_pos = softplus_f(l);
  float sp_neg = softplus_f(-l);
  float ent = p * sp_neg + (1.0f - p) * sp_pos;
  size_t idx = (size_t)(b * Ln + i) * Ln + j;
  out[OFF_MASK + idx] = l;
  out[OFF_SMP + idx] = smp;
  out[OFF_ENT + idx] = ent;
  atomicAdd(&out[OFF_GRAPH + i * Ln + j], smp * 0.0625f);
  float ent_v = ent;
  float lse_v = sp_pos - l * smp;

  // reduce over the 4 waves (all lanes valid)
#pragma unroll
  for (int off = 32; off > 0; off >>= 1) {
    ent_v += __shfl_down(ent_v, off);
    lse_v += __shfl_down(lse_v, off);
  }
  if ((t & 63) == 0) {
    redS[(t >> 6) * 2 + 0] = ent_v;
    redS[(t >> 6) * 2 + 1] = lse_v;
  }
  __syncthreads();
  if (t == 0) {
    float es = redS[0] + redS[2] + redS[4] + redS[6];
    float ls = redS[1] + redS[3] + redS[5] + redS[7];
    atomicAdd(&ws_acc[b], (double)es);
    atomicAdd(&ws_acc[16], (double)ls);
    __threadfence();   // make this block's ws atomics visible before counter
    unsigned int* ctr = (unsigned int*)&ws_acc[17];
    unsigned done = atomicAdd(ctr, 1u);
    if (done == (unsigned)(gridDim.x - 1)) {
      // fused finalize: all blocks' device-scope atomics are complete.
      // atomicAdd(,0.0) = L2-coherent read (bypasses potentially stale L1).
      double ls_tot = atomicAdd(&ws_acc[16], 0.0);
      out[OFF_LSE] = (float)(ls_tot / (double)(Bn * Ln * Ln));
      for (int q = 0; q < Bn; ++q) {
        double ev = atomicAdd(&ws_acc[q], 0.0);
        out[OFF_EREG + q] = (float)(ev / (double)(Ln * Ln));
      }
    }
  }
}

extern "C" void kernel_launch(void* const* d_in, const int* in_sizes, int n_in,
                              void* d_out, int out_size, void* d_ws, size_t ws_size,
                              hipStream_t stream) {
  const float* enc = (const float*)d_in[0];
  const float* Wl = (const float*)d_in[1];
  const float* Wr = (const float*)d_in[2];
  const float* U = (const float*)d_in[3];
  const float* bias = (const float*)d_in[4];
  float* out = (float*)d_out;

  // ws layout: dl (2048*256 f32), dr (2048*256 f32), 17 dbl acc + counter
  float* dl = (float*)d_ws;
  float* dr = dl + (size_t)Bn * Ln * Dn;
  double* ws_acc = (double*)(dr + (size_t)Bn * Ln * Dn);

  proj_kernel<<<512, 256, 0, stream>>>(enc, Wl, Wr, dl, dr, out, ws_acc);
  pair_kernel<<<Bn * Ln / 2, 256, 0, stream>>>(dl, dr, U, bias, out, ws_acc);
}

// Round 7
// 119.005 us; speedup vs baseline: 1.0517x; 1.0517x over previous
//
#include <hip/hip_runtime.h>

#define Bn 16
#define Ln 128
#define Hn 256
#define Dn 256

// Output layout (flat fp32 concat, reference return order)
#define OFF_MASK   0          // (B,L,L) 262144
#define OFF_SMP    262144     // (B,L,L) 262144
#define OFF_ENT    524288     // (B,L,L) 262144
#define OFF_GRAPH  786432     // (L,L)   16384
#define OFF_LSE    802816     // scalar
#define OFF_EREG   802817     // (B,)    16

static __device__ __forceinline__ unsigned rotl32(unsigned x, int r) {
  return (x << r) | (x >> (32 - r));
}

// Threefry-2x32, 20 rounds, key = (0,1)  [jax.random.key(1)], partitionable
// random-bits path: counter = (hi=0, lo=flat_index), output = y0 ^ y1.
static __device__ __forceinline__ unsigned threefry_bits(unsigned c_hi, unsigned c_lo) {
  const unsigned ks0 = 0u, ks1 = 1u;
  const unsigned ks2 = 0u ^ 1u ^ 0x1BD11BDAu;
  unsigned x0 = c_hi + ks0;
  unsigned x1 = c_lo + ks1;
  x0 += x1; x1 = rotl32(x1, 13); x1 ^= x0;
  x0 += x1; x1 = rotl32(x1, 15); x1 ^= x0;
  x0 += x1; x1 = rotl32(x1, 26); x1 ^= x0;
  x0 += x1; x1 = rotl32(x1, 6);  x1 ^= x0;
  x0 += ks1; x1 += ks2 + 1u;
  x0 += x1; x1 = rotl32(x1, 17); x1 ^= x0;
  x0 += x1; x1 = rotl32(x1, 29); x1 ^= x0;
  x0 += x1; x1 = rotl32(x1, 16); x1 ^= x0;
  x0 += x1; x1 = rotl32(x1, 24); x1 ^= x0;
  x0 += ks2; x1 += ks0 + 2u;
  x0 += x1; x1 = rotl32(x1, 13); x1 ^= x0;
  x0 += x1; x1 = rotl32(x1, 15); x1 ^= x0;
  x0 += x1; x1 = rotl32(x1, 26); x1 ^= x0;
  x0 += x1; x1 = rotl32(x1, 6);  x1 ^= x0;
  x0 += ks0; x1 += ks1 + 3u;
  x0 += x1; x1 = rotl32(x1, 17); x1 ^= x0;
  x0 += x1; x1 = rotl32(x1, 29); x1 ^= x0;
  x0 += x1; x1 = rotl32(x1, 16); x1 ^= x0;
  x0 += x1; x1 = rotl32(x1, 24); x1 ^= x0;
  x0 += ks1; x1 += ks2 + 4u;
  x0 += x1; x1 = rotl32(x1, 13); x1 ^= x0;
  x0 += x1; x1 = rotl32(x1, 15); x1 ^= x0;
  x0 += x1; x1 = rotl32(x1, 26); x1 ^= x0;
  x0 += x1; x1 = rotl32(x1, 6);  x1 ^= x0;
  x0 += ks2; x1 += ks0 + 5u;
  return x0 ^ x1;
}

static __device__ __forceinline__ float softplus_f(float x) {
  // max(x,0) + log1p(exp(-|x|)); exact at |x|=1e8 (exp(-1e8)=0)
  return fmaxf(x, 0.0f) + log1pf(__expf(-fabsf(x)));
}

static __device__ __forceinline__ float fast_tanh(float x) {
  // tanh(x) = 2/(1+e^{-2x}) - 1; saturates correctly for |x| large
  float e = __expf(-2.0f * x);
  float r = __builtin_amdgcn_rcpf(1.0f + e);
  return fmaf(2.0f, r, -1.0f);
}

// proj v5 EXACT (best measured; R6's unroll-4 variant cost +16.5us via
// register pressure and is reverted). 512 blocks = (rg:256 x mat:2);
// block = 8 rows x 256 d-cols; thread = 2 rows x 4 cols; float4 W loads,
// wave-uniform scalar enc loads. Chain h-ascending -> dl/dr bit-identical.
__global__ __launch_bounds__(256) void proj_kernel(
                            const float* __restrict__ enc,
                            const float* __restrict__ Wl,
                            const float* __restrict__ Wr,
                            float* __restrict__ dl,
                            float* __restrict__ dr,
                            float* __restrict__ out,
                            double* __restrict__ ws_acc) {
  int gid = blockIdx.x * blockDim.x + threadIdx.x;
  if (gid < Ln * Ln) out[OFF_GRAPH + gid] = 0.0f;
  if (gid < 18) ws_acc[gid] = 0.0;

  int g = blockIdx.x;            // 512 blocks
  int rg = g >> 1;               // 0..255 -> 8-row group
  int mat = g & 1;               // 0 -> Wl/dl, 1 -> Wr/dr
  int r0 = rg * 8;

  int t = threadIdx.x;
  int d4 = (t & 63) * 4;         // 4 consecutive d-cols; lanes -> 1KB coalesced
  int rsub = t >> 6;             // wave id -> row pair

  // wave-uniform row index -> SGPR -> scalar loads of enc
  int row0 = __builtin_amdgcn_readfirstlane(r0 + rsub * 2);
  const float* ep0 = enc + (size_t)row0 * Hn;
  const float* ep1 = ep0 + Hn;
  const float* wbase = (mat ? Wr : Wl) + d4;

  float4 a0 = {0.f, 0.f, 0.f, 0.f};
  float4 a1 = {0.f, 0.f, 0.f, 0.f};

#pragma unroll 2
  for (int h8 = 0; h8 < Hn / 8; ++h8) {
    float4 w[8];
#pragma unroll
    for (int u = 0; u < 8; ++u)
      w[u] = *(const float4*)(wbase + (size_t)(h8 * 8 + u) * Dn);
#pragma unroll
    for (int u = 0; u < 8; ++u) {
      int h = h8 * 8 + u;        // h ascending overall -> same chain order
      float e0 = ep0[h];
      float e1 = ep1[h];
      a0.x = fmaf(e0, w[u].x, a0.x);
      a0.y = fmaf(e0, w[u].y, a0.y);
      a0.z = fmaf(e0, w[u].z, a0.z);
      a0.w = fmaf(e0, w[u].w, a0.w);
      a1.x = fmaf(e1, w[u].x, a1.x);
      a1.y = fmaf(e1, w[u].y, a1.y);
      a1.z = fmaf(e1, w[u].z, a1.z);
      a1.w = fmaf(e1, w[u].w, a1.w);
    }
  }

  float* dst = (mat ? dr : dl) + (size_t)(r0 + rsub * 2) * Dn + d4;
  *(float4*)dst = a0;
  *(float4*)(dst + Dn) = a1;
}

// pair v7: 8 i-rows per block. Grid 512 = (b:16, iq:16, jseg:2); block =
// 64 j x 256 d as before but EIGHT dlr row-chains per dr load. Rationale:
// R6 proved bank conflicts irrelevant (917K->164K, dur flat); pair is
// latency-bound -- per tl, 4 L2 loads (~300cy) fed only 64 tanh-chains
// (~900cy issue). With 8 rows: same 4 loads feed 128 chains (~1800cy) ->
// issue-dominated even at 2 blocks/CU. dr traffic/block unchanged.
// Per-(i,j) chunk order (q,c-ascending) and dp-ascending chunk sum
// IDENTICAL -> outputs bit-identical. launch_bounds(256,2): VGPR cap 256
// for dlr[8][16] (~200 used), no spill.
__global__ __launch_bounds__(256, 2) void pair_kernel(
                            const float* __restrict__ dl,
                            const float* __restrict__ dr,
                            const float* __restrict__ U,
                            const float* __restrict__ bias,
                            float* __restrict__ out,
                            double* __restrict__ ws_acc) {
  int blk = blockIdx.x;          // b*32 + iq*2 + jseg
  int b = blk >> 5;              // 0..15
  int i0 = ((blk >> 1) & 15) * 8;
  int j0 = (blk & 1) * 64;
  int t = threadIdx.x;
  int dp = t & 15;
  int jj = t >> 4;

  __shared__ float dlS[8][16][20];    // 10 KB, padded anti-conflict layout
  __shared__ float pS[8][64 * 17];    // [row][jl*17 + dp], padded, 34 KB
  __shared__ float redS[8];

  // stage dl rows i0..i0+7: 512 float4s, 2 per thread, padded LDS dest
  {
#pragma unroll
    for (int s = 0; s < 2; ++s) {
      int f = (s * 256 + t) * 4;          // global float index in 8x256 tile
      int srow = f >> 8, c = f & 255;
      *(float4*)&dlS[srow][c >> 4][c & 15] =
          ((const float4*)(dl + (size_t)(b * Ln + i0) * Dn))[s * 256 + t];
    }
  }

  float Ur[16];
  {
    const float4* U4 = (const float4*)(U + dp * 16);
#pragma unroll
    for (int q = 0; q < 4; ++q) {
      float4 u = U4[q];
      Ur[4*q+0] = u.x; Ur[4*q+1] = u.y; Ur[4*q+2] = u.z; Ur[4*q+3] = u.w;
    }
  }
  __syncthreads();

  float dlr[8][16];
#pragma unroll
  for (int r = 0; r < 8; ++r) {
#pragma unroll
    for (int q = 0; q < 4; ++q) {
      float4 a = *(const float4*)&dlS[r][dp][q * 4];
      dlr[r][4*q+0] = a.x; dlr[r][4*q+1] = a.y; dlr[r][4*q+2] = a.z; dlr[r][4*q+3] = a.w;
    }
  }

  const float* drt = dr + (size_t)b * Ln * Dn + (size_t)(j0 + jj) * Dn + dp * 16;
#pragma unroll
  for (int tl = 0; tl < 4; ++tl) {
    const float4* drp = (const float4*)(drt + (size_t)tl * 16 * Dn);
    float acc[8] = {0.f, 0.f, 0.f, 0.f, 0.f, 0.f, 0.f, 0.f};
#pragma unroll
    for (int q = 0; q < 4; ++q) {
      float4 v = drp[q];
#pragma unroll
      for (int c = 0; c < 4; ++c) {
        float dv = (c == 0) ? v.x : (c == 1) ? v.y : (c == 2) ? v.z : v.w;
        float uv = Ur[4*q+c];
#pragma unroll
        for (int r = 0; r < 8; ++r)
          acc[r] = fmaf(fast_tanh(dlr[r][4*q+c] + dv), uv, acc[r]);
      }
    }
    int sa = (tl * 16 + jj) * 17 + dp;   // jl*17 + dp, jl = tl*16+jj
#pragma unroll
    for (int r = 0; r < 8; ++r) pS[r][sa] = acc[r];
  }
  __syncthreads();

  // epilogue: 512 outputs (8 rows x 64 j); thread t -> rows {t>>6, t>>6+4},
  // jl = t&63. Per-output formulas identical to prior rounds.
  float ent_v = 0.0f, lse_v = 0.0f;
#pragma unroll
  for (int rr = 0; rr < 2; ++rr) {
    int row = (t >> 6) + rr * 4;
    int jl = t & 63;
    int j = j0 + jl;
    const float* ps = &pS[row][jl * 17];
    float tot = 0.0f;
#pragma unroll
    for (int k = 0; k < 16; ++k) tot += ps[k];   // dp-ascending, same as R9
    int i = i0 + row;
    float l = tot + bias[0] - ((j == i) ? 1.0e8f : 0.0f);
    float e = __expf(-l);                       // l=-1e8 -> inf
    float p = __builtin_amdgcn_rcpf(1.0f + e);  // -> 0 on diagonal
    unsigned n = ((unsigned)(b * Ln + i) << 7) | (unsigned)j;
    unsigned bits = threefry_bits(0u, n);
    float u = __uint_as_float((bits >> 9) | 0x3f800000u) - 1.0f;
    float smp = (u < p) ? 1.0f : 0.0f;
    float sp_pos = softplus_f(l);
    float sp_neg = softplus_f(-l);
    float ent = p * sp_neg + (1.0f - p) * sp_pos;
    size_t idx = (size_t)(b * Ln + i) * Ln + j;
    out[OFF_MASK + idx] = l;
    out[OFF_SMP + idx] = smp;
    out[OFF_ENT + idx] = ent;
    atomicAdd(&out[OFF_GRAPH + i * Ln + j], smp * 0.0625f);
    ent_v += ent;
    lse_v += sp_pos - l * smp;
  }

  // reduce over the 4 waves (all lanes valid)
#pragma unroll
  for (int off = 32; off > 0; off >>= 1) {
    ent_v += __shfl_down(ent_v, off);
    lse_v += __shfl_down(lse_v, off);
  }
  if ((t & 63) == 0) {
    redS[(t >> 6) * 2 + 0] = ent_v;
    redS[(t >> 6) * 2 + 1] = lse_v;
  }
  __syncthreads();
  if (t == 0) {
    float es = redS[0] + redS[2] + redS[4] + redS[6];
    float ls = redS[1] + redS[3] + redS[5] + redS[7];
    atomicAdd(&ws_acc[b], (double)es);
    atomicAdd(&ws_acc[16], (double)ls);
    __threadfence();   // make this block's ws atomics visible before counter
    unsigned int* ctr = (unsigned int*)&ws_acc[17];
    unsigned done = atomicAdd(ctr, 1u);
    if (done == (unsigned)(gridDim.x - 1)) {
      // fused finalize: all blocks' device-scope atomics are complete.
      // atomicAdd(,0.0) = L2-coherent read (bypasses potentially stale L1).
      double ls_tot = atomicAdd(&ws_acc[16], 0.0);
      out[OFF_LSE] = (float)(ls_tot / (double)(Bn * Ln * Ln));
      for (int q = 0; q < Bn; ++q) {
        double ev = atomicAdd(&ws_acc[q], 0.0);
        out[OFF_EREG + q] = (float)(ev / (double)(Ln * Ln));
      }
    }
  }
}

extern "C" void kernel_launch(void* const* d_in, const int* in_sizes, int n_in,
                              void* d_out, int out_size, void* d_ws, size_t ws_size,
                              hipStream_t stream) {
  const float* enc = (const float*)d_in[0];
  const float* Wl = (const float*)d_in[1];
  const float* Wr = (const float*)d_in[2];
  const float* U = (const float*)d_in[3];
  const float* bias = (const float*)d_in[4];
  float* out = (float*)d_out;

  // ws layout: dl (2048*256 f32), dr (2048*256 f32), 17 dbl acc + counter
  float* dl = (float*)d_ws;
  float* dr = dl + (size_t)Bn * Ln * Dn;
  double* ws_acc = (double*)(dr + (size_t)Bn * Ln * Dn);

  proj_kernel<<<512, 256, 0, stream>>>(enc, Wl, Wr, dl, dr, out, ws_acc);
  pair_kernel<<<512, 256, 0, stream>>>(dl, dr, U, bias, out, ws_acc);
}